// Round 6
// baseline (481.909 us; speedup 1.0000x reference)
//
#include <hip/hip_runtime.h>
#include <hip/hip_bf16.h>

#define B_ 2
#define T_ 2048
#define C_ 1280
#define H_ 10
#define D_ 128
#define BT_ (B_*T_)

typedef __hip_bfloat16 bf16;
typedef __attribute__((ext_vector_type(8))) short short8;
typedef __attribute__((ext_vector_type(4))) float f32x4;

__device__ __forceinline__ float bf2f(bf16 v){ return __bfloat162float(v); }
__device__ __forceinline__ bf16  f2bf(float v){ return __float2bfloat16(v); }
__device__ __forceinline__ void stv(bf16* p, float v){ *p = f2bf(v); }
__device__ __forceinline__ void stv(float* p, float v){ *p = v; }

struct alignas(8) bf4 { bf16 a,b,c,d; };

__device__ __forceinline__ void gl2lds(const bf16* g, bf16* l) {
    __builtin_amdgcn_global_load_lds(
        (const __attribute__((address_space(1))) void*)g,
        (__attribute__((address_space(3))) void*)l,
        16, 0, 0);
}

// ---- fp32 -> bf16 bulk convert ----
__global__ __launch_bounds__(256)
void cvt(const float* __restrict__ s, bf16* __restrict__ d)
{
    const int i = (blockIdx.x*256 + threadIdx.x)*4;
    const float4 v = *(const float4*)(s + i);
    bf4 o = { f2bf(v.x), f2bf(v.y), f2bf(v.z), f2bf(v.w) };
    *(bf4*)(d + i) = o;
}

__global__ __launch_bounds__(256)
void cvtW(const float* __restrict__ s0, const float* __restrict__ s1,
          const float* __restrict__ s2, const float* __restrict__ s3,
          bf16* __restrict__ d)
{
    const int w = blockIdx.y;
    const float* s = (w==0)?s0:(w==1)?s1:(w==2)?s2:s3;
    const int i = (blockIdx.x*256 + threadIdx.x)*4;
    const float4 v = *(const float4*)(s + i);
    bf4 o = { f2bf(v.x), f2bf(v.y), f2bf(v.z), f2bf(v.w) };
    *(bf4*)(d + (size_t)w*C_*C_ + i) = o;
}

// ---- GEMM: O = A[4096,1280] @ W[1280,1280]^T, bf16 in, fp32 acc, BK=64 ----
template <typename OT>
__global__ __launch_bounds__(256,3)
void gemm_nt(const bf16* __restrict__ A, const bf16* __restrict__ Wb,
             OT* __restrict__ O0, OT* __restrict__ O1, OT* __restrict__ O2)
{
    __shared__ __align__(16) bf16 As[128*64];
    __shared__ __align__(16) bf16 Bs[128*64];
    const int z = blockIdx.z;
    const bf16* Wm = Wb + (size_t)z*C_*C_;
    OT*         Om = (z==0) ? O0 : (z==1) ? O1 : O2;
    const int wave = threadIdx.x >> 6;
    const int lane = threadIdx.x & 63;
    const int l15 = lane & 15, quad = lane >> 4;
    const int row0 = blockIdx.x*128;
    const int col0 = blockIdx.y*128;
    const int wm = (wave>>1)*64, wn = (wave&1)*64;
    const int srow = lane >> 3;
    const int scol = (lane & 7)*8;

    const f32x4 fzero = {0.f,0.f,0.f,0.f};
    f32x4 acc[4][4];
    #pragma unroll
    for (int i=0;i<4;i++)
        #pragma unroll
        for (int j=0;j<4;j++) acc[i][j] = fzero;

    const bf16* Ag = A  + (size_t)(row0 + wave*32 + srow)*C_ + scol;
    const bf16* Bg = Wm + (size_t)(col0 + wave*32 + srow)*C_ + scol;
    bf16* Al = As + (wave*32)*64;
    bf16* Bl = Bs + (wave*32)*64;

    for (int k0 = 0; k0 < C_; k0 += 64) {
        __syncthreads();
        #pragma unroll
        for (int i=0;i<4;i++){
            gl2lds(Ag + (size_t)i*8*C_ + k0, Al + i*8*64);
            gl2lds(Bg + (size_t)i*8*C_ + k0, Bl + i*8*64);
        }
        asm volatile("s_waitcnt vmcnt(0)" ::: "memory");
        __syncthreads();
        #pragma unroll
        for (int h=0; h<2; ++h) {
            short8 af[4], bfv[4];
            #pragma unroll
            for (int mt=0; mt<4; ++mt) af[mt]  = *(const short8*)(As + (wm + mt*16 + l15)*64 + h*32 + quad*8);
            #pragma unroll
            for (int nt=0; nt<4; ++nt) bfv[nt] = *(const short8*)(Bs + (wn + nt*16 + l15)*64 + h*32 + quad*8);
            #pragma unroll
            for (int mt=0; mt<4; ++mt)
                #pragma unroll
                for (int nt=0; nt<4; ++nt)
                    acc[mt][nt] = __builtin_amdgcn_mfma_f32_16x16x32_bf16(af[mt], bfv[nt], acc[mt][nt], 0,0,0);
        }
    }
    #pragma unroll
    for (int mt=0; mt<4; ++mt)
        #pragma unroll
        for (int nt=0; nt<4; ++nt)
            #pragma unroll
            for (int r=0; r<4; ++r)
                stv(&Om[(size_t)(row0 + wm + mt*16 + quad*4 + r)*C_ + col0 + wn + nt*16 + l15], acc[mt][nt][r]);
}

// ---- RoPE + RMS-norm, in place ----
__global__ __launch_bounds__(256)
void rope_rms(bf16* __restrict__ q, bf16* __restrict__ k,
              const float* __restrict__ cosp, const float* __restrict__ sinp)
{
    const int wave = threadIdx.x >> 6, lane = threadIdx.x & 63;
    const long rb = (long)blockIdx.x*4 + wave;
    const int h = (int)(rb % H_);
    const long bt = rb / H_;
    const int t = (int)(bt % T_);
    bf16* buf = blockIdx.y ? k : q;
    const size_t base = (size_t)bt*C_ + (size_t)h*D_;
    float x1 = bf2f(buf[base + lane]);
    float x2 = bf2f(buf[base + 64 + lane]);
    float c  = cosp[(size_t)t*64 + lane];
    float s  = sinp[(size_t)t*64 + lane];
    float y1 =  x1*c + x2*s;
    float y2 = -x1*s + x2*c;
    float ss = y1*y1 + y2*y2;
    #pragma unroll
    for (int off=1; off<64; off<<=1) ss += __shfl_xor(ss, off);
    float sc = rsqrtf(ss*(1.0f/128.0f) + 1e-5f);
    buf[base + lane]      = f2bf(y1*sc);
    buf[base + 64 + lane] = f2bf(y2*sc);
}

// ---- V transpose: Vt[bh][d][t] ----
__global__ __launch_bounds__(256)
void vtrans(const bf16* __restrict__ V, bf16* __restrict__ Vt)
{
    __shared__ float st[64][65];
    const int tid = threadIdx.x;
    const int bh = blockIdx.z;
    const int b = bh / H_, h = bh % H_;
    const int t0 = blockIdx.x*64, d0 = blockIdx.y*64;
    #pragma unroll
    for (int i=0;i<16;i++){
        int e = tid + i*256;
        int r = e >> 6, dd = e & 63;
        st[r][dd] = bf2f(V[(size_t)(b*T_ + t0 + r)*C_ + h*D_ + d0 + dd]);
    }
    __syncthreads();
    #pragma unroll
    for (int i=0;i<16;i++){
        int e = tid + i*256;
        int dd = e >> 6, r = e & 63;
        Vt[((size_t)bh*D_ + d0 + dd)*T_ + t0 + r] = f2bf(st[r][dd]);
    }
}

// ---- Flash attention v4: 32-row q-tile/block, 4 waves = key-range quarters,
// fixed softmax max, K register double-buffer prefetch, XCD-pair swizzle,
// two-pass in-LDS combine (19 KB LDS). ----
#define M0_ 11.3137085f
__global__ __launch_bounds__(256,3)
void attn(const bf16* __restrict__ Q, const bf16* __restrict__ K,
          const bf16* __restrict__ Vt, bf16* __restrict__ Y)
{
    __shared__ __align__(16) bf16 smem[4][32*72];   // per-wave P-tile / o-partial (union)
    __shared__ float lsh[4][32];
    const int wave = threadIdx.x >> 6, lane = threadIdx.x & 63;
    const int l15 = lane & 15, quad = lane >> 4;
    // XCD-pair swizzle: pair g = (bid&7)>>1 serves bh in [5g, 5g+5)
    const int bid = blockIdx.x;
    const int g = (bid & 7) >> 1;
    const int lidx = ((bid >> 3) << 1) | (bid & 1);     // 0..319 within pair
    const int bh = g*5 + (lidx >> 6);
    const int j  = lidx & 63;
    const int qt = (j & 1) ? (63 - (j >> 1)) : (j >> 1); // interleave for balance
    const int b = bh / H_, h = bh % H_;
    const int t0 = qt*32;
    const int nch = (qt >> 1) + 1;                       // 64-key chunks in causal range
    const int c0 = (wave*nch) >> 2;
    const int c1 = ((wave+1)*nch) >> 2;
    const size_t base = (size_t)b*T_*C_ + (size_t)h*D_;
    const float scale = 0.08838834764831845f;            // 1/sqrt(128)
    bf16* pt = smem[wave];

    short8 qa[2][4];
    #pragma unroll
    for (int tl=0; tl<2; ++tl) {
        const bf16* qp = Q + base + (size_t)(t0 + tl*16 + l15)*C_ + quad*8;
        #pragma unroll
        for (int kb=0; kb<4; ++kb) qa[tl][kb] = *(const short8*)(qp + kb*32);
    }
    const f32x4 fzero = {0.f,0.f,0.f,0.f};
    f32x4 o[2][8];
    #pragma unroll
    for (int tl=0; tl<2; ++tl)
        #pragma unroll
        for (int dt=0; dt<8; ++dt) o[tl][dt] = fzero;
    float lp[2][4] = {{0,0,0,0},{0,0,0,0}};

    auto loadK = [&](int ch, short8 (&kf)[16]) {
        const bf16* kp = K + base + (size_t)(ch*64 + l15)*C_ + quad*8;
        #pragma unroll
        for (int c=0;c<4;c++)
            #pragma unroll
            for (int kb=0;kb<4;kb++)
                kf[c*4+kb] = *(const short8*)(kp + (size_t)(c*16)*C_ + kb*32);
    };
    auto step = [&](int ch, short8 (&kf)[16]) {
        const int k0 = ch*64;
        const bool lastc = (ch == nch-1);
        f32x4 sc4[2][4];
        #pragma unroll
        for (int tl=0; tl<2; ++tl)
            #pragma unroll
            for (int c=0;c<4;c++) sc4[tl][c] = fzero;
        #pragma unroll
        for (int c=0;c<4;c++)
            #pragma unroll
            for (int kb=0; kb<4; ++kb) {
                sc4[0][c] = __builtin_amdgcn_mfma_f32_16x16x32_bf16(qa[0][kb], kf[c*4+kb], sc4[0][c], 0,0,0);
                sc4[1][c] = __builtin_amdgcn_mfma_f32_16x16x32_bf16(qa[1][kb], kf[c*4+kb], sc4[1][c], 0,0,0);
            }
        #pragma unroll
        for (int tl=0; tl<2; ++tl)
            #pragma unroll
            for (int r=0; r<4; ++r) {
                const int rt = t0 + tl*16 + quad*4 + r;
                float v[4];
                #pragma unroll
                for (int c=0;c<4;c++) v[c] = sc4[tl][c][r]*scale;
                if (lastc) {
                    #pragma unroll
                    for (int c=0;c<4;c++) if (k0 + c*16 + l15 > rt) v[c] = -1e30f;
                }
                float p[4];
                #pragma unroll
                for (int c=0;c<4;c++) p[c] = __expf(v[c] - M0_);
                lp[tl][r] += (p[0]+p[1]) + (p[2]+p[3]);
                #pragma unroll
                for (int c=0;c<4;c++) pt[(tl*16+quad*4+r)*72 + c*16 + l15] = f2bf(p[c]);
            }
        asm volatile("s_waitcnt lgkmcnt(0)" ::: "memory");
        short8 pa[2][2];
        #pragma unroll
        for (int tl=0; tl<2; ++tl)
            #pragma unroll
            for (int ks=0; ks<2; ++ks)
                pa[tl][ks] = *(const short8*)(pt + (tl*16+l15)*72 + ks*32 + quad*8);
        const bf16* vp = Vt + ((size_t)bh*D_ + l15)*T_ + k0 + quad*8;
        #pragma unroll
        for (int dt=0; dt<8; ++dt) {
            #pragma unroll
            for (int ks=0; ks<2; ++ks) {
                short8 bV = *(const short8*)(vp + (size_t)dt*16*T_ + ks*32);
                o[0][dt] = __builtin_amdgcn_mfma_f32_16x16x32_bf16(pa[0][ks], bV, o[0][dt], 0,0,0);
                o[1][dt] = __builtin_amdgcn_mfma_f32_16x16x32_bf16(pa[1][ks], bV, o[1][dt], 0,0,0);
            }
        }
    };

    // ping-pong K prefetch
    short8 ka[16], kb16[16];
    if (c0 < c1) loadK(c0, ka);
    int ch = c0;
    while (ch < c1) {
        if (ch+1 < c1) loadK(ch+1, kb16);
        step(ch, ka);
        ++ch;
        if (ch < c1) {
            if (ch+1 < c1) loadK(ch+1, ka);
            step(ch, kb16);
            ++ch;
        }
    }

    // reduce l over the 16-lane group; publish per-wave l
    #pragma unroll
    for (int tl=0; tl<2; ++tl)
        #pragma unroll
        for (int r=0; r<4; ++r) {
            #pragma unroll
            for (int off=1; off<16; off<<=1) lp[tl][r] += __shfl_xor(lp[tl][r], off);
        }
    if (l15 == 0) {
        #pragma unroll
        for (int tl=0; tl<2; ++tl)
            #pragma unroll
            for (int r=0; r<4; ++r) lsh[wave][tl*16 + quad*4 + r] = lp[tl][r];
    }

    // two-pass combine, reusing the 32x72 region per wave
    const int row = threadIdx.x >> 3;
    const int cg8 = (threadIdx.x & 7)*8;
    #pragma unroll
    for (int half=0; half<2; ++half) {
        #pragma unroll
        for (int tl=0; tl<2; ++tl)
            #pragma unroll
            for (int dt=0; dt<4; ++dt)
                #pragma unroll
                for (int r=0; r<4; ++r)
                    pt[(tl*16+quad*4+r)*72 + dt*16 + l15] = f2bf(o[tl][half*4+dt][r]);
        __syncthreads();
        const float li = 1.0f/(lsh[0][row]+lsh[1][row]+lsh[2][row]+lsh[3][row]);
        float s8[8];
        #pragma unroll
        for (int e=0;e<8;e++) s8[e] = 0.f;
        #pragma unroll
        for (int wv=0; wv<4; ++wv) {
            const bf16* pp = smem[wv] + row*72 + cg8;
            #pragma unroll
            for (int e=0;e<8;e++) s8[e] += bf2f(pp[e]);
        }
        bf16 ov[8];
        #pragma unroll
        for (int e=0;e<8;e++) ov[e] = f2bf(s8[e]*li);
        *(short8*)(Y + base + (size_t)(t0 + row)*C_ + half*64 + cg8) = *(short8*)(&ov[0]);
        __syncthreads();
    }
}

extern "C" void kernel_launch(void* const* d_in, const int* in_sizes, int n_in,
                              void* d_out, int out_size, void* d_ws, size_t ws_size,
                              hipStream_t stream)
{
    const float* x    = (const float*)d_in[0];
    const float* cosp = (const float*)d_in[1];
    const float* sinp = (const float*)d_in[2];
    const float* Wq   = (const float*)d_in[3];
    const float* Wk   = (const float*)d_in[4];
    const float* Wv   = (const float*)d_in[5];
    const float* Wp   = (const float*)d_in[6];
    float* out = (float*)d_out;

    const size_t NE = (size_t)BT_ * C_;
    const size_t NW = (size_t)C_ * C_;
    bf16* xb = (bf16*)d_ws;
    bf16* wb = xb + NE;
    bf16* q  = wb + 4*NW;
    bf16* k  = q + NE;
    bf16* v  = k + NE;
    bf16* y  = v + NE;
    bf16* vT = y + NE;

    cvt<<<dim3(NE/1024), 256, 0, stream>>>(x, xb);
    cvtW<<<dim3(NW/1024, 4), 256, 0, stream>>>(Wq, Wk, Wv, Wp, wb);
    gemm_nt<bf16><<<dim3(BT_/128, C_/128, 3), 256, 0, stream>>>(xb, wb, q, k, v);
    rope_rms<<<dim3(BT_*H_/4, 2), 256, 0, stream>>>(q, k, cosp, sinp);
    vtrans<<<dim3(T_/64, D_/64, B_*H_), 256, 0, stream>>>(v, vT);
    attn<<<dim3(B_*H_*64), 256, 0, stream>>>(q, k, vT, y);
    gemm_nt<float><<<dim3(BT_/128, C_/128, 1), 256, 0, stream>>>(y, wb + 3*NW, out, out, out);
}

// Round 7
// 332.644 us; speedup vs baseline: 1.4487x; 1.4487x over previous
//
#include <hip/hip_runtime.h>
#include <hip/hip_bf16.h>

#define B_ 2
#define T_ 2048
#define C_ 1280
#define H_ 10
#define D_ 128
#define BT_ (B_*T_)

typedef __hip_bfloat16 bf16;
typedef __attribute__((ext_vector_type(8))) short short8;
typedef __attribute__((ext_vector_type(4))) float f32x4;

__device__ __forceinline__ float bf2f(bf16 v){ return __bfloat162float(v); }
__device__ __forceinline__ bf16  f2bf(float v){ return __float2bfloat16(v); }
__device__ __forceinline__ void stv(bf16* p, float v){ *p = f2bf(v); }
__device__ __forceinline__ void stv(float* p, float v){ *p = v; }

struct alignas(8) bf4 { bf16 a,b,c,d; };

__device__ __forceinline__ void gl2lds(const bf16* g, bf16* l) {
    __builtin_amdgcn_global_load_lds(
        (const __attribute__((address_space(1))) void*)g,
        (__attribute__((address_space(3))) void*)l,
        16, 0, 0);
}

// ---- fp32 -> bf16 bulk convert ----
__global__ __launch_bounds__(256)
void cvt(const float* __restrict__ s, bf16* __restrict__ d)
{
    const int i = (blockIdx.x*256 + threadIdx.x)*4;
    const float4 v = *(const float4*)(s + i);
    bf4 o = { f2bf(v.x), f2bf(v.y), f2bf(v.z), f2bf(v.w) };
    *(bf4*)(d + i) = o;
}

__global__ __launch_bounds__(256)
void cvtW(const float* __restrict__ s0, const float* __restrict__ s1,
          const float* __restrict__ s2, const float* __restrict__ s3,
          bf16* __restrict__ d)
{
    const int w = blockIdx.y;
    const float* s = (w==0)?s0:(w==1)?s1:(w==2)?s2:s3;
    const int i = (blockIdx.x*256 + threadIdx.x)*4;
    const float4 v = *(const float4*)(s + i);
    bf4 o = { f2bf(v.x), f2bf(v.y), f2bf(v.z), f2bf(v.w) };
    *(bf4*)(d + (size_t)w*C_*C_ + i) = o;
}

// ---- GEMM: O = A[4096,1280] @ W[1280,1280]^T, bf16 in, fp32 acc, BK=64 ----
template <typename OT>
__global__ __launch_bounds__(256,3)
void gemm_nt(const bf16* __restrict__ A, const bf16* __restrict__ Wb,
             OT* __restrict__ O0, OT* __restrict__ O1, OT* __restrict__ O2)
{
    __shared__ __align__(16) bf16 As[128*64];
    __shared__ __align__(16) bf16 Bs[128*64];
    const int z = blockIdx.z;
    const bf16* Wm = Wb + (size_t)z*C_*C_;
    OT*         Om = (z==0) ? O0 : (z==1) ? O1 : O2;
    const int wave = threadIdx.x >> 6;
    const int lane = threadIdx.x & 63;
    const int l15 = lane & 15, quad = lane >> 4;
    const int row0 = blockIdx.x*128;
    const int col0 = blockIdx.y*128;
    const int wm = (wave>>1)*64, wn = (wave&1)*64;
    const int srow = lane >> 3;
    const int scol = (lane & 7)*8;

    const f32x4 fzero = {0.f,0.f,0.f,0.f};
    f32x4 acc[4][4];
    #pragma unroll
    for (int i=0;i<4;i++)
        #pragma unroll
        for (int j=0;j<4;j++) acc[i][j] = fzero;

    const bf16* Ag = A  + (size_t)(row0 + wave*32 + srow)*C_ + scol;
    const bf16* Bg = Wm + (size_t)(col0 + wave*32 + srow)*C_ + scol;
    bf16* Al = As + (wave*32)*64;
    bf16* Bl = Bs + (wave*32)*64;

    for (int k0 = 0; k0 < C_; k0 += 64) {
        __syncthreads();
        #pragma unroll
        for (int i=0;i<4;i++){
            gl2lds(Ag + (size_t)i*8*C_ + k0, Al + i*8*64);
            gl2lds(Bg + (size_t)i*8*C_ + k0, Bl + i*8*64);
        }
        asm volatile("s_waitcnt vmcnt(0)" ::: "memory");
        __syncthreads();
        #pragma unroll
        for (int h=0; h<2; ++h) {
            short8 af[4], bfv[4];
            #pragma unroll
            for (int mt=0; mt<4; ++mt) af[mt]  = *(const short8*)(As + (wm + mt*16 + l15)*64 + h*32 + quad*8);
            #pragma unroll
            for (int nt=0; nt<4; ++nt) bfv[nt] = *(const short8*)(Bs + (wn + nt*16 + l15)*64 + h*32 + quad*8);
            #pragma unroll
            for (int mt=0; mt<4; ++mt)
                #pragma unroll
                for (int nt=0; nt<4; ++nt)
                    acc[mt][nt] = __builtin_amdgcn_mfma_f32_16x16x32_bf16(af[mt], bfv[nt], acc[mt][nt], 0,0,0);
        }
    }
    #pragma unroll
    for (int mt=0; mt<4; ++mt)
        #pragma unroll
        for (int nt=0; nt<4; ++nt)
            #pragma unroll
            for (int r=0; r<4; ++r)
                stv(&Om[(size_t)(row0 + wm + mt*16 + quad*4 + r)*C_ + col0 + wn + nt*16 + l15], acc[mt][nt][r]);
}

// ---- RoPE + RMS-norm, in place ----
__global__ __launch_bounds__(256)
void rope_rms(bf16* __restrict__ q, bf16* __restrict__ k,
              const float* __restrict__ cosp, const float* __restrict__ sinp)
{
    const int wave = threadIdx.x >> 6, lane = threadIdx.x & 63;
    const long rb = (long)blockIdx.x*4 + wave;
    const int h = (int)(rb % H_);
    const long bt = rb / H_;
    const int t = (int)(bt % T_);
    bf16* buf = blockIdx.y ? k : q;
    const size_t base = (size_t)bt*C_ + (size_t)h*D_;
    float x1 = bf2f(buf[base + lane]);
    float x2 = bf2f(buf[base + 64 + lane]);
    float c  = cosp[(size_t)t*64 + lane];
    float s  = sinp[(size_t)t*64 + lane];
    float y1 =  x1*c + x2*s;
    float y2 = -x1*s + x2*c;
    float ss = y1*y1 + y2*y2;
    #pragma unroll
    for (int off=1; off<64; off<<=1) ss += __shfl_xor(ss, off);
    float sc = rsqrtf(ss*(1.0f/128.0f) + 1e-5f);
    buf[base + lane]      = f2bf(y1*sc);
    buf[base + 64 + lane] = f2bf(y2*sc);
}

// ---- V transpose: Vt[bh][d][t] ----
__global__ __launch_bounds__(256)
void vtrans(const bf16* __restrict__ V, bf16* __restrict__ Vt)
{
    __shared__ float st[64][65];
    const int tid = threadIdx.x;
    const int bh = blockIdx.z;
    const int b = bh / H_, h = bh % H_;
    const int t0 = blockIdx.x*64, d0 = blockIdx.y*64;
    #pragma unroll
    for (int i=0;i<16;i++){
        int e = tid + i*256;
        int r = e >> 6, dd = e & 63;
        st[r][dd] = bf2f(V[(size_t)(b*T_ + t0 + r)*C_ + h*D_ + d0 + dd]);
    }
    __syncthreads();
    #pragma unroll
    for (int i=0;i<16;i++){
        int e = tid + i*256;
        int dd = e >> 6, r = e & 63;
        Vt[((size_t)bh*D_ + d0 + dd)*T_ + t0 + r] = f2bf(st[r][dd]);
    }
}

// ---- Flash attention v5: equal-work blocks.
// Tile = 32 q-rows. qt<32: 1 block, 4-way wave split-K, direct y write.
// qt>=32: 2 blocks (key-range halves), 4-way split inside, global partial + combine.
// Fixed softmax max M0 (q,k RMS-normed => score <= sqrt(128)). ----
#define M0_ 11.3137085f
__global__ __launch_bounds__(256,3)
void attn(const bf16* __restrict__ Q, const bf16* __restrict__ K,
          const bf16* __restrict__ Vt, bf16* __restrict__ Y,
          bf16* __restrict__ opart, float* __restrict__ lpart)
{
    __shared__ __align__(16) bf16 smem[4][32*72];   // per-wave P-tile / o-chunks (union)
    __shared__ float lsh[4][32];
    const int wave = threadIdx.x >> 6, lane = threadIdx.x & 63;
    const int l15 = lane & 15, quad = lane >> 4;
    // block decode: bh in [0,20), u in [0,96)
    const int bid = blockIdx.x;
    const int bh = bid / 96;
    const int u  = bid % 96;
    const bool split = (u >= 32);
    const int qt = split ? (32 + ((u-32) >> 1)) : u;
    const int s  = split ? ((u-32) & 1) : 0;
    const int b = bh / H_, h = bh % H_;
    const int t0 = qt*32;
    const int nch = (qt >> 1) + 1;                 // 64-key chunks in causal range
    const int kbeg = split ? (s*nch)>>1 : 0;
    const int kend = split ? ((s+1)*nch)>>1 : nch;
    const int cnt  = kend - kbeg;
    const int c0 = kbeg + ((wave*cnt) >> 2);
    const int c1 = kbeg + (((wave+1)*cnt) >> 2);
    const size_t base = (size_t)b*T_*C_ + (size_t)h*D_;
    const float scale = 0.08838834764831845f;      // 1/sqrt(128)
    bf16* pt = smem[wave];

    short8 qa[2][4];
    #pragma unroll
    for (int tl=0; tl<2; ++tl) {
        const bf16* qp = Q + base + (size_t)(t0 + tl*16 + l15)*C_ + quad*8;
        #pragma unroll
        for (int kb=0; kb<4; ++kb) qa[tl][kb] = *(const short8*)(qp + kb*32);
    }
    const f32x4 fzero = {0.f,0.f,0.f,0.f};
    f32x4 o[2][8];
    #pragma unroll
    for (int tl=0; tl<2; ++tl)
        #pragma unroll
        for (int dt=0; dt<8; ++dt) o[tl][dt] = fzero;
    float lp[2][4] = {{0,0,0,0},{0,0,0,0}};

    for (int ch=c0; ch<c1; ++ch) {
        const int k0 = ch*64;
        const bool lastc = (ch == nch-1);
        f32x4 sc4[2][4];
        #pragma unroll
        for (int tl=0; tl<2; ++tl)
            #pragma unroll
            for (int c=0;c<4;c++) sc4[tl][c] = fzero;
        const bf16* kp = K + base + (size_t)(k0 + l15)*C_ + quad*8;
        #pragma unroll
        for (int c=0;c<4;c++){
            const bf16* kpc = kp + (size_t)(c*16)*C_;
            #pragma unroll
            for (int kb=0; kb<4; ++kb) {
                short8 bK = *(const short8*)(kpc + kb*32);
                sc4[0][c] = __builtin_amdgcn_mfma_f32_16x16x32_bf16(qa[0][kb], bK, sc4[0][c], 0,0,0);
                sc4[1][c] = __builtin_amdgcn_mfma_f32_16x16x32_bf16(qa[1][kb], bK, sc4[1][c], 0,0,0);
            }
        }
        #pragma unroll
        for (int tl=0; tl<2; ++tl)
            #pragma unroll
            for (int r=0; r<4; ++r) {
                const int rt = t0 + tl*16 + quad*4 + r;
                float v[4];
                #pragma unroll
                for (int c=0;c<4;c++) v[c] = sc4[tl][c][r]*scale;
                if (lastc) {
                    #pragma unroll
                    for (int c=0;c<4;c++) if (k0 + c*16 + l15 > rt) v[c] = -1e30f;
                }
                float p[4];
                #pragma unroll
                for (int c=0;c<4;c++) p[c] = __expf(v[c] - M0_);
                lp[tl][r] += (p[0]+p[1]) + (p[2]+p[3]);
                #pragma unroll
                for (int c=0;c<4;c++) pt[(tl*16+quad*4+r)*72 + c*16 + l15] = f2bf(p[c]);
            }
        asm volatile("s_waitcnt lgkmcnt(0)" ::: "memory");   // own wave's P writes visible
        short8 pa[2][2];
        #pragma unroll
        for (int tl=0; tl<2; ++tl)
            #pragma unroll
            for (int ks=0; ks<2; ++ks)
                pa[tl][ks] = *(const short8*)(pt + (tl*16+l15)*72 + ks*32 + quad*8);
        const bf16* vp = Vt + ((size_t)bh*D_ + l15)*T_ + k0 + quad*8;
        #pragma unroll
        for (int dt=0; dt<8; ++dt) {
            #pragma unroll
            for (int ks=0; ks<2; ++ks) {
                short8 bV = *(const short8*)(vp + (size_t)dt*16*T_ + ks*32);
                o[0][dt] = __builtin_amdgcn_mfma_f32_16x16x32_bf16(pa[0][ks], bV, o[0][dt], 0,0,0);
                o[1][dt] = __builtin_amdgcn_mfma_f32_16x16x32_bf16(pa[1][ks], bV, o[1][dt], 0,0,0);
            }
        }
    }
    // reduce l over the 16-lane group; publish per-wave l
    #pragma unroll
    for (int tl=0; tl<2; ++tl)
        #pragma unroll
        for (int r=0; r<4; ++r) {
            #pragma unroll
            for (int off=1; off<16; off<<=1) lp[tl][r] += __shfl_xor(lp[tl][r], off);
        }
    if (l15 == 0) {
        #pragma unroll
        for (int tl=0; tl<2; ++tl)
            #pragma unroll
            for (int r=0; r<4; ++r) lsh[wave][tl*16 + quad*4 + r] = lp[tl][r];
    }

    // two-pass combine over 4 waves, reusing the 32x72 region
    const int slot = split ? (((bh*32 + (qt-32))<<1) | s) : 0;
    const int row = threadIdx.x >> 3;
    const int cg8 = (threadIdx.x & 7)*8;
    #pragma unroll
    for (int half=0; half<2; ++half) {
        #pragma unroll
        for (int tl=0; tl<2; ++tl)
            #pragma unroll
            for (int dt=0; dt<4; ++dt)
                #pragma unroll
                for (int r=0; r<4; ++r)
                    pt[(tl*16+quad*4+r)*72 + dt*16 + l15] = f2bf(o[tl][half*4+dt][r]);
        __syncthreads();
        const float lsum = lsh[0][row]+lsh[1][row]+lsh[2][row]+lsh[3][row];
        float s8[8];
        #pragma unroll
        for (int e=0;e<8;e++) s8[e] = 0.f;
        #pragma unroll
        for (int wv=0; wv<4; ++wv) {
            const bf16* pp = smem[wv] + row*72 + cg8;
            #pragma unroll
            for (int e=0;e<8;e++) s8[e] += bf2f(pp[e]);
        }
        bf16 ov[8];
        if (!split) {
            const float li = 1.0f/lsum;
            #pragma unroll
            for (int e=0;e<8;e++) ov[e] = f2bf(s8[e]*li);
            *(short8*)(Y + base + (size_t)(t0 + row)*C_ + half*64 + cg8) = *(short8*)(&ov[0]);
        } else {
            #pragma unroll
            for (int e=0;e<8;e++) ov[e] = f2bf(s8[e]);
            *(short8*)(opart + (size_t)slot*4096 + row*128 + half*64 + cg8) = *(short8*)(&ov[0]);
            if (half==0 && threadIdx.x < 32) lpart[(size_t)slot*32 + threadIdx.x] = lsh[0][threadIdx.x]+lsh[1][threadIdx.x]+lsh[2][threadIdx.x]+lsh[3][threadIdx.x];
        }
        __syncthreads();
    }
}

// ---- combine the 2 partials for tiles qt>=32 ----
__global__ __launch_bounds__(256)
void combine2(const bf16* __restrict__ opart, const float* __restrict__ lpart,
              bf16* __restrict__ Y)
{
    const int tt = blockIdx.x;            // 0..639: bh*32 + (qt-32)
    const int bh = tt >> 5;
    const int qt = 32 + (tt & 31);
    const int b = bh / H_, h = bh % H_;
    const int t0 = qt*32;
    const int row = threadIdx.x >> 3;
    const int cg8 = (threadIdx.x & 7)*16;
    const float li = 1.0f/(lpart[(size_t)(2*tt)*32 + row] + lpart[(size_t)(2*tt+1)*32 + row]);
    const bf16* p0 = opart + (size_t)(2*tt)*4096   + row*128 + cg8;
    const bf16* p1 = opart + (size_t)(2*tt+1)*4096 + row*128 + cg8;
    bf16 ov[16];
    #pragma unroll
    for (int e=0;e<16;e++) ov[e] = f2bf((bf2f(p0[e]) + bf2f(p1[e]))*li);
    bf16* yp = Y + (size_t)b*T_*C_ + (size_t)(t0+row)*C_ + (size_t)h*D_ + cg8;
    *(short8*)(yp)   = *(short8*)(&ov[0]);
    *(short8*)(yp+8) = *(short8*)(&ov[8]);
}

extern "C" void kernel_launch(void* const* d_in, const int* in_sizes, int n_in,
                              void* d_out, int out_size, void* d_ws, size_t ws_size,
                              hipStream_t stream)
{
    const float* x    = (const float*)d_in[0];
    const float* cosp = (const float*)d_in[1];
    const float* sinp = (const float*)d_in[2];
    const float* Wq   = (const float*)d_in[3];
    const float* Wk   = (const float*)d_in[4];
    const float* Wv   = (const float*)d_in[5];
    const float* Wp   = (const float*)d_in[6];
    float* out = (float*)d_out;

    const size_t NE = (size_t)BT_ * C_;
    const size_t NW = (size_t)C_ * C_;
    bf16* xb = (bf16*)d_ws;
    bf16* wb = xb + NE;
    bf16* q  = wb + 4*NW;
    bf16* k  = q + NE;
    bf16* v  = k + NE;
    bf16* y  = v + NE;
    bf16* vT = y + NE;
    bf16* op = vT + NE;                          // 1280 slots x 4096 bf16 (10.5 MB)
    float* lpart = (float*)(op + (size_t)1280*4096);  // 1280 x 32 f32

    cvt<<<dim3(NE/1024), 256, 0, stream>>>(x, xb);
    cvtW<<<dim3(NW/1024, 4), 256, 0, stream>>>(Wq, Wk, Wv, Wp, wb);
    gemm_nt<bf16><<<dim3(BT_/128, C_/128, 3), 256, 0, stream>>>(xb, wb, q, k, v);
    rope_rms<<<dim3(BT_*H_/4, 2), 256, 0, stream>>>(q, k, cosp, sinp);
    vtrans<<<dim3(T_/64, D_/64, B_*H_), 256, 0, stream>>>(v, vT);
    attn<<<dim3(B_*H_*96), 256, 0, stream>>>(q, k, vT, y, op, lpart);
    combine2<<<dim3(640), 256, 0, stream>>>(op, lpart, y);
    gemm_nt<float><<<dim3(BT_/128, C_/128, 1), 256, 0, stream>>>(y, wb + 3*NW, out, out, out);
}

// Round 8
// 317.004 us; speedup vs baseline: 1.5202x; 1.0493x over previous
//
#include <hip/hip_runtime.h>
#include <hip/hip_bf16.h>

#define B_ 2
#define T_ 2048
#define C_ 1280
#define H_ 10
#define D_ 128
#define BT_ (B_*T_)

typedef __hip_bfloat16 bf16;
typedef __attribute__((ext_vector_type(8))) short short8;
typedef __attribute__((ext_vector_type(4))) float f32x4;

__device__ __forceinline__ float bf2f(bf16 v){ return __bfloat162float(v); }
__device__ __forceinline__ bf16  f2bf(float v){ return __float2bfloat16(v); }
__device__ __forceinline__ void stv(bf16* p, float v){ *p = f2bf(v); }
__device__ __forceinline__ void stv(float* p, float v){ *p = v; }

struct alignas(8) bf4 { bf16 a,b,c,d; };

__device__ __forceinline__ void gl2lds(const bf16* g, bf16* l) {
    __builtin_amdgcn_global_load_lds(
        (const __attribute__((address_space(1))) void*)g,
        (__attribute__((address_space(3))) void*)l,
        16, 0, 0);
}

// ---- fp32 -> bf16 bulk convert ----
__global__ __launch_bounds__(256)
void cvt(const float* __restrict__ s, bf16* __restrict__ d)
{
    const int i = (blockIdx.x*256 + threadIdx.x)*4;
    const float4 v = *(const float4*)(s + i);
    bf4 o = { f2bf(v.x), f2bf(v.y), f2bf(v.z), f2bf(v.w) };
    *(bf4*)(d + i) = o;
}

__global__ __launch_bounds__(256)
void cvtW(const float* __restrict__ s0, const float* __restrict__ s1,
          const float* __restrict__ s2, const float* __restrict__ s3,
          bf16* __restrict__ d)
{
    const int w = blockIdx.y;
    const float* s = (w==0)?s0:(w==1)?s1:(w==2)?s2:s3;
    const int i = (blockIdx.x*256 + threadIdx.x)*4;
    const float4 v = *(const float4*)(s + i);
    bf4 o = { f2bf(v.x), f2bf(v.y), f2bf(v.z), f2bf(v.w) };
    *(bf4*)(d + (size_t)w*C_*C_ + i) = o;
}

// ---- GEMM: O = A[4096,1280] @ W[1280,1280]^T, bf16 in, fp32 acc, BK=64 ----
template <typename OT>
__global__ __launch_bounds__(256,3)
void gemm_nt(const bf16* __restrict__ A, const bf16* __restrict__ Wb,
             OT* __restrict__ O0, OT* __restrict__ O1, OT* __restrict__ O2)
{
    __shared__ __align__(16) bf16 As[128*64];
    __shared__ __align__(16) bf16 Bs[128*64];
    const int z = blockIdx.z;
    const bf16* Wm = Wb + (size_t)z*C_*C_;
    OT*         Om = (z==0) ? O0 : (z==1) ? O1 : O2;
    const int wave = threadIdx.x >> 6;
    const int lane = threadIdx.x & 63;
    const int l15 = lane & 15, quad = lane >> 4;
    const int row0 = blockIdx.x*128;
    const int col0 = blockIdx.y*128;
    const int wm = (wave>>1)*64, wn = (wave&1)*64;
    const int srow = lane >> 3;
    const int scol = (lane & 7)*8;

    const f32x4 fzero = {0.f,0.f,0.f,0.f};
    f32x4 acc[4][4];
    #pragma unroll
    for (int i=0;i<4;i++)
        #pragma unroll
        for (int j=0;j<4;j++) acc[i][j] = fzero;

    const bf16* Ag = A  + (size_t)(row0 + wave*32 + srow)*C_ + scol;
    const bf16* Bg = Wm + (size_t)(col0 + wave*32 + srow)*C_ + scol;
    bf16* Al = As + (wave*32)*64;
    bf16* Bl = Bs + (wave*32)*64;

    for (int k0 = 0; k0 < C_; k0 += 64) {
        __syncthreads();
        #pragma unroll
        for (int i=0;i<4;i++){
            gl2lds(Ag + (size_t)i*8*C_ + k0, Al + i*8*64);
            gl2lds(Bg + (size_t)i*8*C_ + k0, Bl + i*8*64);
        }
        asm volatile("s_waitcnt vmcnt(0)" ::: "memory");
        __syncthreads();
        #pragma unroll
        for (int h=0; h<2; ++h) {
            short8 af[4], bfv[4];
            #pragma unroll
            for (int mt=0; mt<4; ++mt) af[mt]  = *(const short8*)(As + (wm + mt*16 + l15)*64 + h*32 + quad*8);
            #pragma unroll
            for (int nt=0; nt<4; ++nt) bfv[nt] = *(const short8*)(Bs + (wn + nt*16 + l15)*64 + h*32 + quad*8);
            #pragma unroll
            for (int mt=0; mt<4; ++mt)
                #pragma unroll
                for (int nt=0; nt<4; ++nt)
                    acc[mt][nt] = __builtin_amdgcn_mfma_f32_16x16x32_bf16(af[mt], bfv[nt], acc[mt][nt], 0,0,0);
        }
    }
    #pragma unroll
    for (int mt=0; mt<4; ++mt)
        #pragma unroll
        for (int nt=0; nt<4; ++nt)
            #pragma unroll
            for (int r=0; r<4; ++r)
                stv(&Om[(size_t)(row0 + wm + mt*16 + quad*4 + r)*C_ + col0 + wn + nt*16 + l15], acc[mt][nt][r]);
}

// ---- RoPE + RMS-norm, in place ----
__global__ __launch_bounds__(256)
void rope_rms(bf16* __restrict__ q, bf16* __restrict__ k,
              const float* __restrict__ cosp, const float* __restrict__ sinp)
{
    const int wave = threadIdx.x >> 6, lane = threadIdx.x & 63;
    const long rb = (long)blockIdx.x*4 + wave;
    const int h = (int)(rb % H_);
    const long bt = rb / H_;
    const int t = (int)(bt % T_);
    bf16* buf = blockIdx.y ? k : q;
    const size_t base = (size_t)bt*C_ + (size_t)h*D_;
    float x1 = bf2f(buf[base + lane]);
    float x2 = bf2f(buf[base + 64 + lane]);
    float c  = cosp[(size_t)t*64 + lane];
    float s  = sinp[(size_t)t*64 + lane];
    float y1 =  x1*c + x2*s;
    float y2 = -x1*s + x2*c;
    float ss = y1*y1 + y2*y2;
    #pragma unroll
    for (int off=1; off<64; off<<=1) ss += __shfl_xor(ss, off);
    float sc = rsqrtf(ss*(1.0f/128.0f) + 1e-5f);
    buf[base + lane]      = f2bf(y1*sc);
    buf[base + 64 + lane] = f2bf(y2*sc);
}

// ---- V transpose: Vt[bh][d][t] ----
__global__ __launch_bounds__(256)
void vtrans(const bf16* __restrict__ V, bf16* __restrict__ Vt)
{
    __shared__ float st[64][65];
    const int tid = threadIdx.x;
    const int bh = blockIdx.z;
    const int b = bh / H_, h = bh % H_;
    const int t0 = blockIdx.x*64, d0 = blockIdx.y*64;
    #pragma unroll
    for (int i=0;i<16;i++){
        int e = tid + i*256;
        int r = e >> 6, dd = e & 63;
        st[r][dd] = bf2f(V[(size_t)(b*T_ + t0 + r)*C_ + h*D_ + d0 + dd]);
    }
    __syncthreads();
    #pragma unroll
    for (int i=0;i<16;i++){
        int e = tid + i*256;
        int dd = e >> 6, r = e & 63;
        Vt[((size_t)bh*D_ + d0 + dd)*T_ + t0 + r] = f2bf(st[r][dd]);
    }
}

// ---- Flash attention v6: equal-work blocks + batched one-latency loads.
// Tile = 32 q-rows. qt<32: 1 block, 4-way wave split-K. qt>=32: 2 blocks + combine.
// Fixed softmax max M0 (q,k RMS-normed => score <= sqrt(128)).
// launch_bounds(256,2): ~212 VGPR budget so all 32 chunk loads batch in-flight. ----
#define M0_ 11.3137085f
__global__ __launch_bounds__(256,2)
void attn(const bf16* __restrict__ Q, const bf16* __restrict__ K,
          const bf16* __restrict__ Vt, bf16* __restrict__ Y,
          bf16* __restrict__ opart, float* __restrict__ lpart)
{
    __shared__ __align__(16) bf16 smem[4][32*72];   // per-wave P-tile / o-chunks (union)
    __shared__ float lsh[4][32];
    const int wave = threadIdx.x >> 6, lane = threadIdx.x & 63;
    const int l15 = lane & 15, quad = lane >> 4;
    const int bid = blockIdx.x;
    const int bh = bid / 96;
    const int u  = bid % 96;
    const bool split = (u >= 32);
    const int qt = split ? (32 + ((u-32) >> 1)) : u;
    const int s  = split ? ((u-32) & 1) : 0;
    const int b = bh / H_, h = bh % H_;
    const int t0 = qt*32;
    const int nch = (qt >> 1) + 1;                 // 64-key chunks in causal range
    const int kbeg = split ? (s*nch)>>1 : 0;
    const int kend = split ? ((s+1)*nch)>>1 : nch;
    const int cnt  = kend - kbeg;
    const int c0 = kbeg + ((wave*cnt) >> 2);
    const int c1 = kbeg + (((wave+1)*cnt) >> 2);
    const size_t base = (size_t)b*T_*C_ + (size_t)h*D_;
    const float scale = 0.08838834764831845f;      // 1/sqrt(128)
    bf16* pt = smem[wave];

    short8 qa[2][4];
    #pragma unroll
    for (int tl=0; tl<2; ++tl) {
        const bf16* qp = Q + base + (size_t)(t0 + tl*16 + l15)*C_ + quad*8;
        #pragma unroll
        for (int kb=0; kb<4; ++kb) qa[tl][kb] = *(const short8*)(qp + kb*32);
    }
    const f32x4 fzero = {0.f,0.f,0.f,0.f};
    f32x4 o[2][8];
    #pragma unroll
    for (int tl=0; tl<2; ++tl)
        #pragma unroll
        for (int dt=0; dt<8; ++dt) o[tl][dt] = fzero;
    float lp[2][4] = {{0,0,0,0},{0,0,0,0}};

    for (int ch=c0; ch<c1; ++ch) {
        const int k0 = ch*64;
        const bool lastc = (ch == nch-1);
        // batch-issue ALL loads for this chunk: V first (needed last), then K.
        // One memory latency total instead of one per load-pair.
        short8 vf[16], kf[16];
        const bf16* vp = Vt + ((size_t)bh*D_ + l15)*T_ + k0 + quad*8;
        #pragma unroll
        for (int dt=0; dt<8; ++dt) {
            vf[dt*2]   = *(const short8*)(vp + (size_t)dt*16*T_);
            vf[dt*2+1] = *(const short8*)(vp + (size_t)dt*16*T_ + 32);
        }
        const bf16* kp = K + base + (size_t)(k0 + l15)*C_ + quad*8;
        #pragma unroll
        for (int c=0;c<4;c++)
            #pragma unroll
            for (int kb=0; kb<4; ++kb)
                kf[c*4+kb] = *(const short8*)(kp + (size_t)(c*16)*C_ + kb*32);

        f32x4 sc4[2][4];
        #pragma unroll
        for (int tl=0; tl<2; ++tl)
            #pragma unroll
            for (int c=0;c<4;c++) sc4[tl][c] = fzero;
        #pragma unroll
        for (int c=0;c<4;c++)
            #pragma unroll
            for (int kb=0; kb<4; ++kb) {
                sc4[0][c] = __builtin_amdgcn_mfma_f32_16x16x32_bf16(qa[0][kb], kf[c*4+kb], sc4[0][c], 0,0,0);
                sc4[1][c] = __builtin_amdgcn_mfma_f32_16x16x32_bf16(qa[1][kb], kf[c*4+kb], sc4[1][c], 0,0,0);
            }
        #pragma unroll
        for (int tl=0; tl<2; ++tl)
            #pragma unroll
            for (int r=0; r<4; ++r) {
                const int rt = t0 + tl*16 + quad*4 + r;
                float v[4];
                #pragma unroll
                for (int c=0;c<4;c++) v[c] = sc4[tl][c][r]*scale;
                if (lastc) {
                    #pragma unroll
                    for (int c=0;c<4;c++) if (k0 + c*16 + l15 > rt) v[c] = -1e30f;
                }
                float p[4];
                #pragma unroll
                for (int c=0;c<4;c++) p[c] = __expf(v[c] - M0_);
                lp[tl][r] += (p[0]+p[1]) + (p[2]+p[3]);
                #pragma unroll
                for (int c=0;c<4;c++) pt[(tl*16+quad*4+r)*72 + c*16 + l15] = f2bf(p[c]);
            }
        asm volatile("s_waitcnt lgkmcnt(0)" ::: "memory");   // own wave's P writes visible
        short8 pa[2][2];
        #pragma unroll
        for (int tl=0; tl<2; ++tl)
            #pragma unroll
            for (int ks=0; ks<2; ++ks)
                pa[tl][ks] = *(const short8*)(pt + (tl*16+l15)*72 + ks*32 + quad*8);
        #pragma unroll
        for (int dt=0; dt<8; ++dt) {
            #pragma unroll
            for (int ks=0; ks<2; ++ks) {
                o[0][dt] = __builtin_amdgcn_mfma_f32_16x16x32_bf16(pa[0][ks], vf[dt*2+ks], o[0][dt], 0,0,0);
                o[1][dt] = __builtin_amdgcn_mfma_f32_16x16x32_bf16(pa[1][ks], vf[dt*2+ks], o[1][dt], 0,0,0);
            }
        }
    }
    // reduce l over the 16-lane group; publish per-wave l
    #pragma unroll
    for (int tl=0; tl<2; ++tl)
        #pragma unroll
        for (int r=0; r<4; ++r) {
            #pragma unroll
            for (int off=1; off<16; off<<=1) lp[tl][r] += __shfl_xor(lp[tl][r], off);
        }
    if (l15 == 0) {
        #pragma unroll
        for (int tl=0; tl<2; ++tl)
            #pragma unroll
            for (int r=0; r<4; ++r) lsh[wave][tl*16 + quad*4 + r] = lp[tl][r];
    }

    // two-pass combine over 4 waves, reusing the 32x72 region
    const int slot = split ? (((bh*32 + (qt-32))<<1) | s) : 0;
    const int row = threadIdx.x >> 3;
    const int cg8 = (threadIdx.x & 7)*8;
    #pragma unroll
    for (int half=0; half<2; ++half) {
        #pragma unroll
        for (int tl=0; tl<2; ++tl)
            #pragma unroll
            for (int dt=0; dt<4; ++dt)
                #pragma unroll
                for (int r=0; r<4; ++r)
                    pt[(tl*16+quad*4+r)*72 + dt*16 + l15] = f2bf(o[tl][half*4+dt][r]);
        __syncthreads();
        const float lsum = lsh[0][row]+lsh[1][row]+lsh[2][row]+lsh[3][row];
        float s8[8];
        #pragma unroll
        for (int e=0;e<8;e++) s8[e] = 0.f;
        #pragma unroll
        for (int wv=0; wv<4; ++wv) {
            const bf16* pp = smem[wv] + row*72 + cg8;
            #pragma unroll
            for (int e=0;e<8;e++) s8[e] += bf2f(pp[e]);
        }
        bf16 ov[8];
        if (!split) {
            const float li = 1.0f/lsum;
            #pragma unroll
            for (int e=0;e<8;e++) ov[e] = f2bf(s8[e]*li);
            *(short8*)(Y + base + (size_t)(t0 + row)*C_ + half*64 + cg8) = *(short8*)(&ov[0]);
        } else {
            #pragma unroll
            for (int e=0;e<8;e++) ov[e] = f2bf(s8[e]);
            *(short8*)(opart + (size_t)slot*4096 + row*128 + half*64 + cg8) = *(short8*)(&ov[0]);
            if (half==0 && threadIdx.x < 32) lpart[(size_t)slot*32 + threadIdx.x] = lsh[0][threadIdx.x]+lsh[1][threadIdx.x]+lsh[2][threadIdx.x]+lsh[3][threadIdx.x];
        }
        __syncthreads();
    }
}

// ---- combine the 2 partials for tiles qt>=32 ----
__global__ __launch_bounds__(256)
void combine2(const bf16* __restrict__ opart, const float* __restrict__ lpart,
              bf16* __restrict__ Y)
{
    const int tt = blockIdx.x;            // 0..639: bh*32 + (qt-32)
    const int bh = tt >> 5;
    const int qt = 32 + (tt & 31);
    const int b = bh / H_, h = bh % H_;
    const int t0 = qt*32;
    const int row = threadIdx.x >> 3;
    const int cg8 = (threadIdx.x & 7)*16;
    const float li = 1.0f/(lpart[(size_t)(2*tt)*32 + row] + lpart[(size_t)(2*tt+1)*32 + row]);
    const bf16* p0 = opart + (size_t)(2*tt)*4096   + row*128 + cg8;
    const bf16* p1 = opart + (size_t)(2*tt+1)*4096 + row*128 + cg8;
    bf16 ov[16];
    #pragma unroll
    for (int e=0;e<16;e++) ov[e] = f2bf((bf2f(p0[e]) + bf2f(p1[e]))*li);
    bf16* yp = Y + (size_t)b*T_*C_ + (size_t)(t0+row)*C_ + (size_t)h*D_ + cg8;
    *(short8*)(yp)   = *(short8*)(&ov[0]);
    *(short8*)(yp+8) = *(short8*)(&ov[8]);
}

extern "C" void kernel_launch(void* const* d_in, const int* in_sizes, int n_in,
                              void* d_out, int out_size, void* d_ws, size_t ws_size,
                              hipStream_t stream)
{
    const float* x    = (const float*)d_in[0];
    const float* cosp = (const float*)d_in[1];
    const float* sinp = (const float*)d_in[2];
    const float* Wq   = (const float*)d_in[3];
    const float* Wk   = (const float*)d_in[4];
    const float* Wv   = (const float*)d_in[5];
    const float* Wp   = (const float*)d_in[6];
    float* out = (float*)d_out;

    const size_t NE = (size_t)BT_ * C_;
    const size_t NW = (size_t)C_ * C_;
    bf16* xb = (bf16*)d_ws;
    bf16* wb = xb + NE;
    bf16* q  = wb + 4*NW;
    bf16* k  = q + NE;
    bf16* v  = k + NE;
    bf16* y  = v + NE;
    bf16* vT = y + NE;
    bf16* op = vT + NE;                          // 1280 slots x 4096 bf16 (10.5 MB)
    float* lpart = (float*)(op + (size_t)1280*4096);  // 1280 x 32 f32

    cvt<<<dim3(NE/1024), 256, 0, stream>>>(x, xb);
    cvtW<<<dim3(NW/1024, 4), 256, 0, stream>>>(Wq, Wk, Wv, Wp, wb);
    gemm_nt<bf16><<<dim3(BT_/128, C_/128, 3), 256, 0, stream>>>(xb, wb, q, k, v);
    rope_rms<<<dim3(BT_*H_/4, 2), 256, 0, stream>>>(q, k, cosp, sinp);
    vtrans<<<dim3(T_/64, D_/64, B_*H_), 256, 0, stream>>>(v, vT);
    attn<<<dim3(B_*H_*96), 256, 0, stream>>>(q, k, vT, y, op, lpart);
    combine2<<<dim3(640), 256, 0, stream>>>(op, lpart, y);
    gemm_nt<float><<<dim3(BT_/128, C_/128, 1), 256, 0, stream>>>(y, wb + 3*NW, out, out, out);
}